// Round 2
// baseline (303.227 us; speedup 1.0000x reference)
//
#include <hip/hip_runtime.h>

// FeatLUT: out[f] = quantize( mean_p( msb[idx_m(p)][f] + lsb[idx_l(p)][f] ) )
// idx = 16*(289*c0 + 17*c1 + c2)  -> only 17^3 = 4913 distinct rows used.
//
// R3: R2 regressed 3x because __launch_bounds__(512,8) squeezed VGPRs 52->28,
// serializing the load bundles (VALUBusy 6%, 283 GB/s, warm-L3 replay still
// 178us). Fix: 256-thread blocks with (256,6) budget=85 VGPR, 2048 blocks ->
// exactly 2 grid-stride iters FULLY UNROLLED (12 float4 in flight per wave,
// 2x R1's MLP) x ~24-32 waves/CU (packed 19.7KB hist). Phase B: restore the
// empty-bin skip (43% empty at 4096 px/block). Partials -> 20 global atomic
// sums (keeps ws at 236KB), last-block finalize.

#define NBINS 4913            // 17^3
#define NPIX  (2048 * 2048)   // 4194304
#define G4    (NPIX / 4)      // 1048576 float4 groups per channel plane
#define NFEAT 20
#define MB    2048            // main grid
#define MT    256             // MB*MT*2 == G4 exactly: 2 iters, no tail

// ws layout:
//   cc      @ 0      : 4913 * 12 dwords = 235824 B (48B rows: m0..m4 l0..l4 p p)
//   sums    @ 235824 : 20 ints
//   counter @ 235904 : 1 uint

// ---------------------------------------------------------------------------
// Kernel 0: compact used LUT rows (row 16j, j in [0,4913)) into interleaved
// 48-byte rows; zeroes sums + counter (ws is poisoned each iteration).
// Handles both harness layouts (raw int8 bytes vs widened int32): random
// packed bytes essentially never stay in [-32,32) 64x in a row.
// ---------------------------------------------------------------------------
__global__ __launch_bounds__(256) void compact_k(const int* __restrict__ msb,
                                                 const int* __restrict__ lsb,
                                                 int* __restrict__ cc,
                                                 int* __restrict__ sums,
                                                 unsigned* __restrict__ counter) {
    if (blockIdx.x == 0) {
        if (threadIdx.x < NFEAT) sums[threadIdx.x] = 0;
        if (threadIdx.x == NFEAT) *counter = 0u;
    }

    int ok = 1;
    for (int i = 0; i < 64; ++i) {
        int v = msb[i];
        ok &= (v >= -32 && v < 32);
    }
    const bool is_int32 = (ok != 0);

    const int total = NBINS * 10;                 // 49130 source dwords
    int t = blockIdx.x * 256 + threadIdx.x;       // grid 192*256 = 49152 >= total
    if (t >= total) return;
    int j = t / 10;
    int k = t - j * 10;                           // 0-4: msb dword, 5-9: lsb dword
    const int* base = (k < 5) ? msb : lsb;
    int kk = (k < 5) ? k : k - 5;
    int w;
    if (is_int32) {
        // int per element; row 16j starts at element 16j*20 = 320j
        const int* r = base + j * 320 + kk * 4;
        w = (int)((unsigned)(r[0] & 0xff) | ((unsigned)(r[1] & 0xff) << 8) |
                  ((unsigned)(r[2] & 0xff) << 16) | ((unsigned)(r[3] & 0xff) << 24));
    } else {
        // raw int8; row 16j at byte 320j -> dword 80j, 5 dwords/row
        w = base[j * 80 + kk];
    }
    cc[j * 12 + k] = w;                           // pads (10,11) never read
}

// sign-extend byte lane of packed dword
#define SX(w, sh) ((int)((unsigned)(w) << (sh)) >> 24)
// h <= 2048, byte in [-128,127]: product < 2^23, fits v_mad_i32_i24 (full-rate)
#define MACW(h, w, base)                                \
    acc[(base) + 0] += __mul24((h), SX((w), 24));       \
    acc[(base) + 1] += __mul24((h), SX((w), 16));       \
    acc[(base) + 2] += __mul24((h), SX((w), 8));        \
    acc[(base) + 3] += __mul24((h), ((int)(w) >> 24));

#define IDX4(d, v0, v1, v2)                                      \
    int d##0 = (int)fmaf(v0.x, 289.0f, fmaf(v1.x, 17.0f, v2.x)); \
    int d##1 = (int)fmaf(v0.y, 289.0f, fmaf(v1.y, 17.0f, v2.y)); \
    int d##2 = (int)fmaf(v0.z, 289.0f, fmaf(v1.z, 17.0f, v2.z)); \
    int d##3 = (int)fmaf(v0.w, 289.0f, fmaf(v1.w, 17.0f, v2.w));

__device__ __forceinline__ int wave_red(int v) {
#pragma unroll
    for (int o = 32; o > 0; o >>= 1) v += __shfl_xor(v, o, 64);
    return v;
}

// ---------------------------------------------------------------------------
// Kernel 1: main. MB x MT. Packed hist (msb lo16, lsb hi16; per-block pixel
// count per table = 256*2*4 = 2048 < 2^16). Both iters' loads issued up front
// (12 x dwordx4 in flight). Per-block dot with empty-bin skip, 20 atomic
// sums, last block finalizes.
// ---------------------------------------------------------------------------
__global__ __launch_bounds__(MT, 6) void feat_main(const float* __restrict__ xin,
                                                   const float* __restrict__ xs,
                                                   const int* __restrict__ cc,
                                                   int* __restrict__ sums,
                                                   unsigned* __restrict__ counter,
                                                   float* __restrict__ out) {
    __shared__ int hist[NBINS];                 // 19652 B
    __shared__ int wsum[MT / 64][NFEAT];        // 320 B
    __shared__ unsigned last_s;

    for (int i = threadIdx.x; i < NBINS; i += MT) hist[i] = 0;
    __syncthreads();

    const float4* a = (const float4*)xin;
    const float4* b = (const float4*)xs;
    const int g0 = blockIdx.x * MT + threadIdx.x;
    const int g1 = g0 + MB * MT;                // second (and last) trip

    // issue all 12 loads before any use: 192 B/wave in flight
    float4 A00 = a[g0], A01 = a[g0 + G4], A02 = a[g0 + 2 * G4];
    float4 B00 = b[g0], B01 = b[g0 + G4], B02 = b[g0 + 2 * G4];
    float4 A10 = a[g1], A11 = a[g1 + G4], A12 = a[g1 + 2 * G4];
    float4 B10 = b[g1], B11 = b[g1 + G4], B12 = b[g1 + 2 * G4];

    IDX4(m, A00, A01, A02)
    IDX4(s, B00, B01, B02)
    atomicAdd(&hist[m0], 1);
    atomicAdd(&hist[m1], 1);
    atomicAdd(&hist[m2], 1);
    atomicAdd(&hist[m3], 1);
    atomicAdd(&hist[s0], 1 << 16);
    atomicAdd(&hist[s1], 1 << 16);
    atomicAdd(&hist[s2], 1 << 16);
    atomicAdd(&hist[s3], 1 << 16);

    IDX4(n, A10, A11, A12)
    IDX4(t, B10, B11, B12)
    atomicAdd(&hist[n0], 1);
    atomicAdd(&hist[n1], 1);
    atomicAdd(&hist[n2], 1);
    atomicAdd(&hist[n3], 1);
    atomicAdd(&hist[t0], 1 << 16);
    atomicAdd(&hist[t1], 1 << 16);
    atomicAdd(&hist[t2], 1 << 16);
    atomicAdd(&hist[t3], 1 << 16);
    __syncthreads();

    // per-block dot: acc[f] += hm[j]*msb_row[j][f] + hl[j]*lsb_row[j][f]
    // ~43% of bins empty at 4096 px/block -> skip saves cc L2 traffic.
    int acc[NFEAT];
#pragma unroll
    for (int f = 0; f < NFEAT; ++f) acc[f] = 0;

    for (int j = threadIdx.x; j < NBINS; j += MT) {   // 19-20 iters
        int h = hist[j];
        if (h == 0) continue;
        int hm = h & 0xffff;
        int hl = (int)((unsigned)h >> 16);
        const int4* r = (const int4*)(cc + j * 12);    // 48B row, 16B-aligned
        int4 q0 = r[0], q1 = r[1], q2 = r[2];
        MACW(hm, q0.x, 0)  MACW(hm, q0.y, 4)  MACW(hm, q0.z, 8)
        MACW(hm, q0.w, 12) MACW(hm, q1.x, 16)
        MACW(hl, q1.y, 0)  MACW(hl, q1.z, 4)  MACW(hl, q1.w, 8)
        MACW(hl, q2.x, 12) MACW(hl, q2.y, 16)
    }

    // wave butterfly -> per-wave LDS row -> thread f sums 4 -> atomic row
    const int lane = threadIdx.x & 63;
    const int wv = threadIdx.x >> 6;
#pragma unroll
    for (int f = 0; f < NFEAT; ++f) {
        int v = wave_red(acc[f]);
        if (lane == 0) wsum[wv][f] = v;
    }
    __syncthreads();
    if (threadIdx.x < NFEAT) {
        int s = 0;
#pragma unroll
        for (int w = 0; w < MT / 64; ++w) s += wsum[w][threadIdx.x];
        atomicAdd(&sums[threadIdx.x], s);   // 20 addresses, device-scope
    }

    // last-block finalize (fence + device-scope counter; no spin).
    __threadfence();
    __syncthreads();
    if (threadIdx.x == 0) last_s = atomicAdd(counter, 1u);
    __syncthreads();
    if (last_s != MB - 1) return;

    if (threadIdx.x < NFEAT) {
        int s = atomicAdd(&sums[threadIdx.x], 0);   // coherent device-scope read
        // mean*4 = S / 2^20 exactly; RNE rint == jnp.round
        double m4 = (double)s * (1.0 / 1048576.0);
        double r = rint(m4);
        float v = (float)(r * 0.25);
        v = fminf(fmaxf(v, -32.0f), 31.75f);
        out[threadIdx.x] = v;
    }
}

extern "C" void kernel_launch(void* const* d_in, const int* in_sizes, int n_in,
                              void* d_out, int out_size, void* d_ws, size_t ws_size,
                              hipStream_t stream) {
    const float* xin = (const float*)d_in[0];
    const float* xs = (const float*)d_in[1];
    const int* msb = (const int*)d_in[2];
    const int* lsb = (const int*)d_in[3];
    float* out = (float*)d_out;

    int* cc = (int*)d_ws;
    int* sums = (int*)((char*)d_ws + 235824);
    unsigned* counter = (unsigned*)((char*)d_ws + 235904);

    compact_k<<<192, 256, 0, stream>>>(msb, lsb, cc, sums, counter);
    feat_main<<<MB, MT, 0, stream>>>(xin, xs, cc, sums, counter, out);
}